// Round 14
// baseline (227.456 us; speedup 1.0000x reference)
//
#include <hip/hip_runtime.h>
#include <hip/hip_bf16.h>
#include <math.h>

typedef __attribute__((ext_vector_type(8))) short short8;
typedef __attribute__((ext_vector_type(4))) short short4v;
typedef __attribute__((ext_vector_type(4))) float floatx4;
using bf16 = __hip_bfloat16;

#define DEVI __device__ __forceinline__

DEVI floatx4 fzero4() { floatx4 z; z[0]=0.f; z[1]=0.f; z[2]=0.f; z[3]=0.f; return z; }

// hardware exp2: v_exp_f32 computes 2^x (ISA §3).
DEVI float ex2(float x) {
  float r;
  asm("v_exp_f32 %0, %1" : "=v"(r) : "v"(x));
  return r;
}

// 3-input max, single VOP3 inst (T17).
DEVI float max3f(float a, float b, float c) {
  float d;
  asm("v_max3_f32 %0, %1, %2, %3" : "=v"(d) : "v"(a), "v"(b), "v"(c));
  return d;
}

DEVI unsigned short f2b(float x) {
  union { bf16 h; unsigned short u; } c;
  c.h = __float2bfloat16(x);
  return c.u;
}

// K=16 bf16 MFMA: A-frag = 4 bf16 at k=lg*4+j -- matches QK C/D output layout.
DEVI floatx4 mfma16(short4v a, short4v b, floatx4 c) {
#if __has_builtin(__builtin_amdgcn_mfma_f32_16x16x16bf16_1k)
  return __builtin_amdgcn_mfma_f32_16x16x16bf16_1k(a, b, c, 0, 0, 0);
#else
  floatx4 d;
  asm("v_mfma_f32_16x16x16_bf16 %0, %1, %2, %3" : "=v"(d) : "v"(a), "v"(b), "v"(c));
  return d;
#endif
}

// async global->LDS, 16B per lane; lds dest must be wave-uniform base (+lane*16 implicit)
DEVI void gload16(const bf16* g, bf16* l) {
  typedef __attribute__((address_space(1))) const void gv_t;
  typedef __attribute__((address_space(3))) void lv_t;
  __builtin_amdgcn_global_load_lds((gv_t*)g, (lv_t*)l, 16, 0, 0);
}

// ---------------- cast f32 -> bf16 (8 elems/thread, vectorized) ----------------
__global__ __launch_bounds__(256) void k_cast(const float* __restrict__ in,
                                              bf16* __restrict__ out, int n) {
  int i = (blockIdx.x * 256 + threadIdx.x) * 8;
  if (i >= n) return;
  float4 a = *(const float4*)(in + i);
  float4 b = *(const float4*)(in + i + 4);
  short8 v;
  v[0] = (short)f2b(a.x); v[1] = (short)f2b(a.y);
  v[2] = (short)f2b(a.z); v[3] = (short)f2b(a.w);
  v[4] = (short)f2b(b.x); v[5] = (short)f2b(b.y);
  v[6] = (short)f2b(b.z); v[7] = (short)f2b(b.w);
  *(short8*)(out + i) = v;
}

// ---------------- transpose + cast: out[c][r] = in[r][c] ----------------
__global__ __launch_bounds__(256) void k_transpose(const float* __restrict__ in,
                                                   bf16* __restrict__ out,
                                                   int R, int C) {
  __shared__ float tile[32][33];
  int x = blockIdx.x * 32 + threadIdx.x;
  for (int i = threadIdx.y; i < 32; i += 8) {
    int y = blockIdx.y * 32 + i;
    tile[i][threadIdx.x] = (y < R && x < C) ? in[(size_t)y * C + x] : 0.f;
  }
  __syncthreads();
  int ox = blockIdx.y * 32 + threadIdx.x;
  for (int i = threadIdx.y; i < 32; i += 8) {
    int oy = blockIdx.x * 32 + i;
    if (oy < C && ox < R) out[(size_t)oy * R + ox] = __float2bfloat16(tile[threadIdx.x][i]);
  }
}

// ---------------- GEMM1: 8-phase 256x256 tile, BK=64, 8 waves (1M x 8N) ----------------
// Per wave: all 256 M-rows x 32 N-cols -> acc[16][2].  Phase p computes m-quarter p
// (4 m-frags x 2 n-frags x 2 k = 16 MFMA).  A staged in 4 row-quarters (1 gload rnd
// each), B in 2 row-halves (2 rnds each): 8 rnds/tile = 2/phase, staged for tile T+1
// during tile T (always the other dbuf -> write-safe).  vmcnt(4)/phase guarantees
// every operand >=2 stage-slots old (ledger-verified).  Chunk-XOR swizzle (T2) on
// both stage source and ds_read: slot s of row r holds global chunk s^(r&7) ->
// b128 reads at row-stride 128B spread across banks (2-way pairs, free).  T5 setprio.
#define LOG2E_O8 0.18033688011112042f

__global__ __launch_bounds__(512) void k_gemm8(
    const bf16* __restrict__ A, const bf16* __restrict__ Bt,
    const float* __restrict__ bias,
    bf16* __restrict__ Qo, bf16* __restrict__ Ko, bf16* __restrict__ Vo) {
  __shared__ bf16 sA[2][16384];   // 4 quarters x 64 rows x 64 k (chunk-swizzled)
  __shared__ bf16 sB[2][16384];   // 2 halves x 128 rows x 64 k
  const int Kd = 1024;
  const int tid = threadIdx.x;
  const int w = tid >> 6, l = tid & 63;
  const int lg = l >> 4, li = l & 15;
  // XCD-bijective swizzle: 384 blocks, xcd owns by in [xcd*4, xcd*4+4)
  const int ii = blockIdx.x >> 3, xcd = blockIdx.x & 7;
  const int by = xcd * 4 + (ii & 3), bx = ii >> 2;
  const int m0 = by * 256, n0 = bx * 256;

  const int arow = tid >> 3;                 // 0..63
  const int acs = (tid & 7) ^ (arow & 7);    // swizzled source chunk
  const int swz = (li & 7);                  // read-side swizzle key

  // A quarter q (rows q*64..+63), 1 round
  auto STAGE_A = [&](int buf, int k0, int q) {
    gload16(A + (size_t)(m0 + q * 64 + arow) * Kd + k0 + acs * 8,
            &sA[buf][q * 4096 + w * 512]);
  };
  // B half h (rows h*128..+127), 2 rounds
  auto STAGE_B = [&](int buf, int k0, int h) {
    gload16(Bt + (size_t)(n0 + h * 128 + arow) * Kd + k0 + acs * 8,
            &sB[buf][h * 8192 + w * 512]);
    gload16(Bt + (size_t)(n0 + h * 128 + 64 + arow) * Kd + k0 + acs * 8,
            &sB[buf][h * 8192 + 4096 + w * 512]);
  };

  floatx4 acc[16][2];
#pragma unroll
  for (int i = 0; i < 16; ++i) { acc[i][0] = fzero4(); acc[i][1] = fzero4(); }
  short8 bfr[2][2];   // B-frags: live across the 4 phases of a tile

  // prologue: tile 0 fully staged (8 loads)
  STAGE_B(0, 0, 0); STAGE_B(0, 0, 1);
  STAGE_A(0, 0, 0); STAGE_A(0, 0, 1); STAGE_A(0, 0, 2); STAGE_A(0, 0, 3);

#define GPHASE(P)                                                               \
  {                                                                             \
    if (pf) {                                                                   \
      if (P == 0) STAGE_B(nxt, k1, 0);                                          \
      if (P == 1) STAGE_B(nxt, k1, 1);                                          \
      if (P == 2) { STAGE_A(nxt, k1, 0); STAGE_A(nxt, k1, 1); }                 \
      if (P == 3) { STAGE_A(nxt, k1, 2); STAGE_A(nxt, k1, 3); }                 \
      asm volatile("s_waitcnt vmcnt(4)" ::: "memory");                          \
    } else {                                                                    \
      asm volatile("s_waitcnt vmcnt(0)" ::: "memory");                          \
    }                                                                           \
    __builtin_amdgcn_s_barrier();                                               \
    if (P == 0) {                                                               \
      _Pragma("unroll")                                                         \
      for (int j = 0; j < 2; ++j) {                                             \
        const int rb = w * 32 + j * 16 + li;                                    \
        const int h = rb >> 7, rl = rb & 127;                                   \
        _Pragma("unroll")                                                       \
        for (int kc = 0; kc < 2; ++kc)                                          \
          bfr[j][kc] = *(const short8*)&sB[cur][h * 8192 + rl * 64 +            \
                                               (((kc * 4 + lg) ^ swz) * 8)];    \
      }                                                                         \
    }                                                                           \
    short8 af[4][2];                                                            \
    _Pragma("unroll")                                                           \
    for (int i2 = 0; i2 < 4; ++i2)                                              \
      _Pragma("unroll")                                                         \
      for (int kc = 0; kc < 2; ++kc)                                            \
        af[i2][kc] = *(const short8*)&sA[cur][P * 4096 + (i2 * 16 + li) * 64 +  \
                                              (((kc * 4 + lg) ^ swz) * 8)];     \
    __builtin_amdgcn_s_setprio(1);                                              \
    _Pragma("unroll")                                                           \
    for (int i2 = 0; i2 < 4; ++i2)                                              \
      _Pragma("unroll")                                                         \
      for (int j = 0; j < 2; ++j) {                                             \
        acc[P * 4 + i2][j] = __builtin_amdgcn_mfma_f32_16x16x32_bf16(           \
            af[i2][0], bfr[j][0], acc[P * 4 + i2][j], 0, 0, 0);                 \
        acc[P * 4 + i2][j] = __builtin_amdgcn_mfma_f32_16x16x32_bf16(           \
            af[i2][1], bfr[j][1], acc[P * 4 + i2][j], 0, 0, 0);                 \
      }                                                                         \
    __builtin_amdgcn_s_setprio(0);                                              \
    __builtin_amdgcn_s_barrier();                                               \
  }

  int cur = 0;
  for (int T = 0; T < 16; ++T) {
    const int k1 = (T + 1) << 6;
    const int nxt = cur ^ 1;
    const bool pf = (T + 1 < 16);
    GPHASE(0)
    GPHASE(1)
    GPHASE(2)
    GPHASE(3)
    cur = nxt;
  }
#undef GPHASE

  // epilogue: ng = n0 + w*32 + j*16 + li; rows mgb = m0 + i*16 + lg*4 (+r)
  // Q scaled to exp2 domain; V stored transposed with short4 vector along t.
#pragma unroll
  for (int i = 0; i < 16; ++i) {
#pragma unroll
    for (int j = 0; j < 2; ++j) {
      const int ng = n0 + w * 32 + j * 16 + li;
      const float bs = bias[ng];
      const int mgb = m0 + i * 16 + lg * 4;
      const int bb = mgb >> 11, t = mgb & 2047;
      const int d = ng & 63;
      if (ng < 1024) {
        const int h = ng >> 6;
#pragma unroll
        for (int r = 0; r < 4; ++r)
          Qo[(((size_t)bb * 16 + h) * 2048 + t + r) * 64 + d] =
              __float2bfloat16((acc[i][j][r] + bs) * LOG2E_O8);
      } else if (ng < 2048) {
        const int h = (ng - 1024) >> 6;
#pragma unroll
        for (int r = 0; r < 4; ++r)
          Ko[(((size_t)bb * 16 + h) * 2048 + t + r) * 64 + d] =
              __float2bfloat16(acc[i][j][r] + bs);
      } else {
        const int h = (ng - 2048) >> 6;
        short4v vv;
#pragma unroll
        for (int r = 0; r < 4; ++r) vv[r] = (short)f2b(acc[i][j][r] + bs);
        *(short4v*)&Vo[(((size_t)bb * 16 + h) * 64 + d) * 2048 + t] = vv;
      }
    }
  }
}

// ---------------- GEMM v2 (GEMM2 only): 128x128, BK=32, counted vmcnt dbuf ----------------
__global__ __launch_bounds__(256) void k_gemm(
    const bf16* __restrict__ A, const bf16* __restrict__ Bt,
    const float* __restrict__ bias, float* __restrict__ Fo, int N, int Kd) {
  __shared__ bf16 sA[2][128 * 32];
  __shared__ bf16 sB[2][128 * 32];
  const int tid = threadIdx.x;
  const int w = tid >> 6, l = tid & 63;
  const int lg = l >> 4, li = l & 15;
  const int wr = w >> 1, wc = w & 1;
  const int ii = blockIdx.x >> 3, xcd = blockIdx.x & 7;
  const int bx = ii >> 3, by = xcd * 8 + (ii & 7);
  const int m0 = by * 128, n0 = bx * 128;

  const int r0 = tid >> 2, ko0 = (tid & 3) * 8;
  const bf16* pa0 = A + (size_t)(m0 + r0) * Kd + ko0;
  const bf16* pa1 = A + (size_t)(m0 + 64 + r0) * Kd + ko0;
  const bf16* pb0 = Bt + (size_t)(n0 + r0) * Kd + ko0;
  const bf16* pb1 = Bt + (size_t)(n0 + 64 + r0) * Kd + ko0;

  floatx4 acc[4][4];
#pragma unroll
  for (int i = 0; i < 4; ++i)
#pragma unroll
    for (int j = 0; j < 4; ++j) acc[i][j] = fzero4();

  auto STAGE = [&](int buf, int k0) {
    gload16(pa0 + k0, &sA[buf][w * 512]);
    gload16(pa1 + k0, &sA[buf][2048 + w * 512]);
    gload16(pb0 + k0, &sB[buf][w * 512]);
    gload16(pb1 + k0, &sB[buf][2048 + w * 512]);
  };

  STAGE(0, 0);
  int cur = 0;
  for (int k0 = 0; k0 < Kd; k0 += 32) {
    if (k0 + 32 < Kd) {
      STAGE(cur ^ 1, k0 + 32);
      asm volatile("s_waitcnt vmcnt(4)" ::: "memory");
    } else {
      asm volatile("s_waitcnt vmcnt(0)" ::: "memory");
    }
    __builtin_amdgcn_s_barrier();
    short8 af[4], bfr[4];
#pragma unroll
    for (int i = 0; i < 4; ++i)
      af[i] = *(const short8*)&sA[cur][(wr * 64 + i * 16 + li) * 32 + lg * 8];
#pragma unroll
    for (int j = 0; j < 4; ++j)
      bfr[j] = *(const short8*)&sB[cur][(wc * 64 + j * 16 + li) * 32 + lg * 8];
#pragma unroll
    for (int i = 0; i < 4; ++i)
#pragma unroll
      for (int j = 0; j < 4; ++j)
        acc[i][j] = __builtin_amdgcn_mfma_f32_16x16x32_bf16(af[i], bfr[j], acc[i][j], 0, 0, 0);
    __builtin_amdgcn_s_barrier();
    cur ^= 1;
  }

#pragma unroll
  for (int i = 0; i < 4; ++i) {
#pragma unroll
    for (int j = 0; j < 4; ++j) {
      const int ng = n0 + wc * 64 + j * 16 + li;
      const float bs = bias[ng];
      const int mgb = m0 + wr * 64 + i * 16 + lg * 4;
#pragma unroll
      for (int r = 0; r < 4; ++r)
        Fo[(size_t)(mgb + r) * N + ng] = acc[i][j][r] + bs;
    }
  }
}

// ---------------- flash attention v7 (unchanged from round 12) ----------------
#define T_SEQ 2048

__global__ __launch_bounds__(256) void k_attn(
    const bf16* __restrict__ Q, const bf16* __restrict__ K,
    const bf16* __restrict__ Vt, bf16* __restrict__ Y) {
  __shared__ bf16 sK[2][64 * 64];
  __shared__ bf16 sV[2][64 * 64];

  const int tid = threadIdx.x;
  const int w = tid >> 6, l = tid & 63;
  const int lg = l >> 4, li = l & 15;
  const int bid = blockIdx.x;
  const int sq = bid >> 3;
  const int bh = (bid & 7) * 8 + (sq & 7);
  const int g = sq >> 3;
  const int qd = g >> 2, rr = g & 3;
  const int tb = (qd == 0) ? 15 - rr : (qd == 1) ? 8 + rr : (qd == 2) ? 7 - rr : rr;
  const int b = bh >> 4, h = bh & 15;

  const bf16* Qp = Q + (size_t)bh * (T_SEQ * 64);
  const bf16* Kp = K + (size_t)bh * (T_SEQ * 64);
  const bf16* Vp = Vt + (size_t)bh * (64 * T_SEQ);

  const int q0 = tb * 128;
  const int wq0 = q0 + w * 32;
  const int nst = (q0 + 128) >> 6;

  short8 aq[2][2];
#pragma unroll
  for (int rg = 0; rg < 2; ++rg)
#pragma unroll
    for (int dc = 0; dc < 2; ++dc)
      aq[rg][dc] = *(const short8*)(Qp + (size_t)(wq0 + rg * 16 + li) * 64 + dc * 32 + lg * 8);

  floatx4 o[2][4];
#pragma unroll
  for (int rg = 0; rg < 2; ++rg)
#pragma unroll
    for (int f = 0; f < 4; ++f) o[rg][f] = fzero4();
  float m[2] = {-INFINITY, -INFINITY};
  float lsum[2] = {0.f, 0.f};

  auto STAGE = [&](int buf, int k0) {
#pragma unroll
    for (int half = 0; half < 2; ++half) {
      const int c = half * 256 + tid;
      const int row = c >> 3, cs = c & 7;
      const int sc = cs ^ (row & 7);
      bf16* kb = &sK[buf][(half * 256 + w * 64) * 8];
      bf16* vb = &sV[buf][(half * 256 + w * 64) * 8];
      gload16(Kp + (size_t)(k0 + row) * 64 + sc * 8, kb);
      gload16(Vp + (size_t)row * T_SEQ + k0 + sc * 8, vb);
    }
  };

  int cur = 0;
  STAGE(0, 0);
  for (int t = 0; t < nst; ++t) {
    const int k0 = t << 6;
    if (t + 1 < nst) {
      STAGE(cur ^ 1, k0 + 64);
      asm volatile("s_waitcnt vmcnt(4)" ::: "memory");
    } else {
      asm volatile("s_waitcnt vmcnt(0)" ::: "memory");
    }
    __builtin_amdgcn_s_barrier();
    if (k0 <= wq0 + 31) {
      floatx4 s[2][4];
      __builtin_amdgcn_s_setprio(1);
#pragma unroll
      for (int kt = 0; kt < 4; ++kt) {
        const int rowk = kt * 16 + li;
        const short8 kb0 = *(const short8*)&sK[cur][rowk * 64 + ((lg ^ (rowk & 7)) * 8)];
        const short8 kb1 = *(const short8*)&sK[cur][rowk * 64 + (((4 + lg) ^ (rowk & 7)) * 8)];
#pragma unroll
        for (int rg = 0; rg < 2; ++rg) {
          floatx4 acc = __builtin_amdgcn_mfma_f32_16x16x32_bf16(kb0, aq[rg][0], fzero4(), 0, 0, 0);
          s[rg][kt] = __builtin_amdgcn_mfma_f32_16x16x32_bf16(kb1, aq[rg][1], acc, 0, 0, 0);
        }
      }
      __builtin_amdgcn_s_setprio(0);
      if (k0 + 63 > wq0) {
#pragma unroll
        for (int rg = 0; rg < 2; ++rg) {
          const int qg = wq0 + rg * 16 + li;
#pragma unroll
          for (int kt = 0; kt < 4; ++kt) {
            const int kgb = k0 + kt * 16 + lg * 4;
#pragma unroll
            for (int r = 0; r < 4; ++r)
              if (kgb + r > qg) s[rg][kt][r] = -1e30f;
          }
        }
      }
      float pm[2];
#pragma unroll
      for (int rg = 0; rg < 2; ++rg) {
        float t0 = max3f(s[rg][0][0], s[rg][0][1], s[rg][0][2]);
        float t1 = max3f(s[rg][0][3], s[rg][1][0], s[rg][1][1]);
        float t2 = max3f(s[rg][1][2], s[rg][1][3], s[rg][2][0]);
        float t3 = max3f(s[rg][2][1], s[rg][2][2], s[rg][2][3]);
        float t4 = max3f(s[rg][3][0], s[rg][3][1], s[rg][3][2]);
        float p = fmaxf(max3f(t0, t1, t2), max3f(t3, t4, s[rg][3][3]));
        p = fmaxf(p, __shfl_xor(p, 16));
        p = fmaxf(p, __shfl_xor(p, 32));
        pm[rg] = p;
      }
      const float need = fmaxf(pm[0] - m[0], pm[1] - m[1]);
      if (!__all(need <= 8.0f)) {
#pragma unroll
        for (int rg = 0; rg < 2; ++rg) {
          const float mn = fmaxf(m[rg], pm[rg]);
          const float a = ex2(m[rg] - mn);
          m[rg] = mn;
          lsum[rg] *= a;
          float ar[4];
#pragma unroll
          for (int r = 0; r < 4; ++r) ar[r] = __shfl(a, lg * 4 + r);
#pragma unroll
          for (int f = 0; f < 4; ++f) {
            o[rg][f][0] *= ar[0]; o[rg][f][1] *= ar[1];
            o[rg][f][2] *= ar[2]; o[rg][f][3] *= ar[3];
          }
        }
      }
      short4v pa4[2][4];
#pragma unroll
      for (int rg = 0; rg < 2; ++rg) {
#pragma unroll
        for (int kt = 0; kt < 4; ++kt) {
          const float e0 = ex2(s[rg][kt][0] - m[rg]);
          const float e1 = ex2(s[rg][kt][1] - m[rg]);
          const float e2 = ex2(s[rg][kt][2] - m[rg]);
          const float e3 = ex2(s[rg][kt][3] - m[rg]);
          lsum[rg] += (e0 + e1) + (e2 + e3);
          short4v pv;
          pv[0] = (short)f2b(e0); pv[1] = (short)f2b(e1);
          pv[2] = (short)f2b(e2); pv[3] = (short)f2b(e3);
          pa4[rg][kt] = pv;
        }
      }
      __builtin_amdgcn_s_setprio(1);
#pragma unroll
      for (int f = 0; f < 4; ++f) {
        const int rowv = f * 16 + li;
        const int rx = rowv & 7;
#pragma unroll
        for (int kt = 0; kt < 4; ++kt) {
          const int cc = 2 * kt + (lg >> 1);
          const short4v vb4 = *(const short4v*)&sV[cur][rowv * 64 + (((cc ^ rx) << 3) | ((lg & 1) << 2))];
          o[0][f] = mfma16(pa4[0][kt], vb4, o[0][f]);
          o[1][f] = mfma16(pa4[1][kt], vb4, o[1][f]);
        }
      }
      __builtin_amdgcn_s_setprio(0);
    }
    __builtin_amdgcn_s_barrier();
    cur ^= 1;
  }
#pragma unroll
  for (int rg = 0; rg < 2; ++rg) {
    float Ls = lsum[rg];
    Ls += __shfl_xor(Ls, 16);
    Ls += __shfl_xor(Ls, 32);
#pragma unroll
    for (int r = 0; r < 4; ++r) {
      const float inv = 1.0f / __shfl(Ls, lg * 4 + r);
      const int qg = wq0 + rg * 16 + lg * 4 + r;
      const size_t base = ((size_t)b * T_SEQ + qg) * 1024 + h * 64;
#pragma unroll
      for (int f = 0; f < 4; ++f)
        Y[base + f * 16 + li] = __float2bfloat16(o[rg][f][r] * inv);
    }
  }
}

// ---------------- launch ----------------
extern "C" void kernel_launch(void* const* d_in, const int* in_sizes, int n_in,
                              void* d_out, int out_size, void* d_ws, size_t ws_size,
                              hipStream_t stream) {
  const float* x      = (const float*)d_in[0];
  const float* W_attn = (const float*)d_in[1];
  const float* b_attn = (const float*)d_in[2];
  const float* W_proj = (const float*)d_in[3];
  const float* b_proj = (const float*)d_in[4];
  float* out = (float*)d_out;

  char* ws = (char*)d_ws;
  bf16* Wt_a = (bf16*)(ws);
  bf16* Wt_p = (bf16*)(ws + 6291456);
  bf16* Qb   = (bf16*)(ws + 8388608);
  bf16* Kb   = (bf16*)(ws + 25165824);
  bf16* Vtb  = (bf16*)(ws + 41943040);
  bf16* x_bf = (bf16*)(ws + 58720256);
  bf16* Yb   = x_bf;  // alias: x_bf dead after GEMM1

  k_cast<<<4096, 256, 0, stream>>>(x, x_bf, 8388608);
  k_transpose<<<dim3(96, 32), dim3(32, 8), 0, stream>>>(W_attn, Wt_a, 1024, 3072);
  k_transpose<<<dim3(32, 32), dim3(32, 8), 0, stream>>>(W_proj, Wt_p, 1024, 1024);
  // GEMM1: 8-phase 256^2, grid 12x32 = 384 blocks of 512 threads
  k_gemm8<<<384, 512, 0, stream>>>(x_bf, Wt_a, b_attn, Qb, Kb, Vtb);
  k_attn<<<1024, 256, 0, stream>>>(Qb, Kb, Vtb, Yb);
  // GEMM2: v2 128^2, 8x64 = 512 blocks
  k_gemm<<<512, 256, 0, stream>>>(Yb, Wt_p, b_proj, out, 1024, 1024);
}

// Round 15
// 204.417 us; speedup vs baseline: 1.1127x; 1.1127x over previous
//
#include <hip/hip_runtime.h>
#include <hip/hip_bf16.h>
#include <math.h>

typedef __attribute__((ext_vector_type(8))) short short8;
typedef __attribute__((ext_vector_type(4))) short short4v;
typedef __attribute__((ext_vector_type(4))) float floatx4;
using bf16 = __hip_bfloat16;

#define DEVI __device__ __forceinline__

DEVI floatx4 fzero4() { floatx4 z; z[0]=0.f; z[1]=0.f; z[2]=0.f; z[3]=0.f; return z; }

// hardware exp2: v_exp_f32 computes 2^x (ISA §3).
DEVI float ex2(float x) {
  float r;
  asm("v_exp_f32 %0, %1" : "=v"(r) : "v"(x));
  return r;
}

// 3-input max, single VOP3 inst (T17).
DEVI float max3f(float a, float b, float c) {
  float d;
  asm("v_max3_f32 %0, %1, %2, %3" : "=v"(d) : "v"(a), "v"(b), "v"(c));
  return d;
}

DEVI unsigned short f2b(float x) {
  union { bf16 h; unsigned short u; } c;
  c.h = __float2bfloat16(x);
  return c.u;
}

// K=16 bf16 MFMA: A-frag = 4 bf16 at k=lg*4+j -- matches QK C/D output layout.
DEVI floatx4 mfma16(short4v a, short4v b, floatx4 c) {
#if __has_builtin(__builtin_amdgcn_mfma_f32_16x16x16bf16_1k)
  return __builtin_amdgcn_mfma_f32_16x16x16bf16_1k(a, b, c, 0, 0, 0);
#else
  floatx4 d;
  asm("v_mfma_f32_16x16x16_bf16 %0, %1, %2, %3" : "=v"(d) : "v"(a), "v"(b), "v"(c));
  return d;
#endif
}

// async global->LDS, 16B per lane; lds dest must be wave-uniform base (+lane*16 implicit)
DEVI void gload16(const bf16* g, bf16* l) {
  typedef __attribute__((address_space(1))) const void gv_t;
  typedef __attribute__((address_space(3))) void lv_t;
  __builtin_amdgcn_global_load_lds((gv_t*)g, (lv_t*)l, 16, 0, 0);
}

// ---------------- cast f32 -> bf16 (8 elems/thread, vectorized) ----------------
__global__ __launch_bounds__(256) void k_cast(const float* __restrict__ in,
                                              bf16* __restrict__ out, int n) {
  int i = (blockIdx.x * 256 + threadIdx.x) * 8;
  if (i >= n) return;
  float4 a = *(const float4*)(in + i);
  float4 b = *(const float4*)(in + i + 4);
  short8 v;
  v[0] = (short)f2b(a.x); v[1] = (short)f2b(a.y);
  v[2] = (short)f2b(a.z); v[3] = (short)f2b(a.w);
  v[4] = (short)f2b(b.x); v[5] = (short)f2b(b.y);
  v[6] = (short)f2b(b.z); v[7] = (short)f2b(b.w);
  *(short8*)(out + i) = v;
}

// ---------------- transpose + cast: out[c][r] = in[r][c] ----------------
__global__ __launch_bounds__(256) void k_transpose(const float* __restrict__ in,
                                                   bf16* __restrict__ out,
                                                   int R, int C) {
  __shared__ float tile[32][33];
  int x = blockIdx.x * 32 + threadIdx.x;
  for (int i = threadIdx.y; i < 32; i += 8) {
    int y = blockIdx.y * 32 + i;
    tile[i][threadIdx.x] = (y < R && x < C) ? in[(size_t)y * C + x] : 0.f;
  }
  __syncthreads();
  int ox = blockIdx.y * 32 + threadIdx.x;
  for (int i = threadIdx.y; i < 32; i += 8) {
    int oy = blockIdx.x * 32 + i;
    if (oy < C && ox < R) out[(size_t)oy * R + ox] = __float2bfloat16(tile[threadIdx.x][i]);
  }
}

// ---------------- GEMM1: 8-phase 256x256 tile, BK=64, 8 waves (1M x 8N) ----------------
// Round-15 wait fix (T4 done right): waits only at P0 (vmcnt(4)) and P2 (vmcnt(6)) --
// each load gets 3-4 phases to land vs 1-2 before; single barrier per phase (64 vs
// 128).  Ledger (steady state, loads/tile in order B0h0,B0h1,B1h0,B1h1,A0,A1,A2,A3):
//   P0 entry <=8 outstanding, +2 (B0 of T+1) -> wait<=4 retires T loads 1-6
//     (B all + A0 + A1: covers P0's B-frags+A0 and P1's A1).
//   P1: +2 -> <=6, no wait.  P2: +2 -> <=8, wait<=6 retires T loads 7,8 (A2,A3).
//   P3: +2 -> <=8 = exactly tile T+1's loads: matches entry invariant.
// Single-barrier safety: stage always writes buf nxt; a wave entering T+1 phase p
// has passed T+1's p-1 barrier, so every cross-buffer write region's last reader
// is >=1 barrier behind (hand-checked per region).
#define LOG2E_O8 0.18033688011112042f

__global__ __launch_bounds__(512) void k_gemm8(
    const bf16* __restrict__ A, const bf16* __restrict__ Bt,
    const float* __restrict__ bias,
    bf16* __restrict__ Qo, bf16* __restrict__ Ko, bf16* __restrict__ Vo) {
  __shared__ bf16 sA[2][16384];   // 4 quarters x 64 rows x 64 k (chunk-swizzled)
  __shared__ bf16 sB[2][16384];   // 2 halves x 128 rows x 64 k
  const int Kd = 1024;
  const int tid = threadIdx.x;
  const int w = tid >> 6, l = tid & 63;
  const int lg = l >> 4, li = l & 15;
  // XCD-bijective swizzle: 384 blocks, xcd owns by in [xcd*4, xcd*4+4)
  const int ii = blockIdx.x >> 3, xcd = blockIdx.x & 7;
  const int by = xcd * 4 + (ii & 3), bx = ii >> 2;
  const int m0 = by * 256, n0 = bx * 256;

  const int arow = tid >> 3;                 // 0..63
  const int acs = (tid & 7) ^ (arow & 7);    // swizzled source chunk
  const int swz = (li & 7);                  // read-side swizzle key

  // A quarter q (rows q*64..+63), 1 round
  auto STAGE_A = [&](int buf, int k0, int q) {
    gload16(A + (size_t)(m0 + q * 64 + arow) * Kd + k0 + acs * 8,
            &sA[buf][q * 4096 + w * 512]);
  };
  // B half h (rows h*128..+127), 2 rounds
  auto STAGE_B = [&](int buf, int k0, int h) {
    gload16(Bt + (size_t)(n0 + h * 128 + arow) * Kd + k0 + acs * 8,
            &sB[buf][h * 8192 + w * 512]);
    gload16(Bt + (size_t)(n0 + h * 128 + 64 + arow) * Kd + k0 + acs * 8,
            &sB[buf][h * 8192 + 4096 + w * 512]);
  };

  floatx4 acc[16][2];
#pragma unroll
  for (int i = 0; i < 16; ++i) { acc[i][0] = fzero4(); acc[i][1] = fzero4(); }
  short8 bfr[2][2];   // B-frags: live across the 4 phases of a tile

  // prologue: tile 0 fully staged (8 loads)
  STAGE_B(0, 0, 0); STAGE_B(0, 0, 1);
  STAGE_A(0, 0, 0); STAGE_A(0, 0, 1); STAGE_A(0, 0, 2); STAGE_A(0, 0, 3);

#define GPHASE(P)                                                               \
  {                                                                             \
    if (pf) {                                                                   \
      if (P == 0) STAGE_B(nxt, k1, 0);                                          \
      if (P == 1) STAGE_B(nxt, k1, 1);                                          \
      if (P == 2) { STAGE_A(nxt, k1, 0); STAGE_A(nxt, k1, 1); }                 \
      if (P == 3) { STAGE_A(nxt, k1, 2); STAGE_A(nxt, k1, 3); }                 \
      if (P == 0) asm volatile("s_waitcnt vmcnt(4)" ::: "memory");              \
      if (P == 2) asm volatile("s_waitcnt vmcnt(6)" ::: "memory");              \
    } else {                                                                    \
      if (P == 0) asm volatile("s_waitcnt vmcnt(2)" ::: "memory");              \
      if (P == 2) asm volatile("s_waitcnt vmcnt(0)" ::: "memory");              \
    }                                                                           \
    __builtin_amdgcn_s_barrier();                                               \
    if (P == 0) {                                                               \
      _Pragma("unroll")                                                         \
      for (int j = 0; j < 2; ++j) {                                             \
        const int rb = w * 32 + j * 16 + li;                                    \
        const int h = rb >> 7, rl = rb & 127;                                   \
        _Pragma("unroll")                                                       \
        for (int kc = 0; kc < 2; ++kc)                                          \
          bfr[j][kc] = *(const short8*)&sB[cur][h * 8192 + rl * 64 +            \
                                               (((kc * 4 + lg) ^ swz) * 8)];    \
      }                                                                         \
    }                                                                           \
    short8 af[4][2];                                                            \
    _Pragma("unroll")                                                           \
    for (int i2 = 0; i2 < 4; ++i2)                                              \
      _Pragma("unroll")                                                         \
      for (int kc = 0; kc < 2; ++kc)                                            \
        af[i2][kc] = *(const short8*)&sA[cur][P * 4096 + (i2 * 16 + li) * 64 +  \
                                              (((kc * 4 + lg) ^ swz) * 8)];     \
    __builtin_amdgcn_s_setprio(1);                                              \
    _Pragma("unroll")                                                           \
    for (int i2 = 0; i2 < 4; ++i2)                                              \
      _Pragma("unroll")                                                         \
      for (int j = 0; j < 2; ++j) {                                             \
        acc[P * 4 + i2][j] = __builtin_amdgcn_mfma_f32_16x16x32_bf16(           \
            af[i2][0], bfr[j][0], acc[P * 4 + i2][j], 0, 0, 0);                 \
        acc[P * 4 + i2][j] = __builtin_amdgcn_mfma_f32_16x16x32_bf16(           \
            af[i2][1], bfr[j][1], acc[P * 4 + i2][j], 0, 0, 0);                 \
      }                                                                         \
    __builtin_amdgcn_s_setprio(0);                                              \
  }

  int cur = 0;
  for (int T = 0; T < 16; ++T) {
    const int k1 = (T + 1) << 6;
    const int nxt = cur ^ 1;
    const bool pf = (T + 1 < 16);
    GPHASE(0)
    GPHASE(1)
    GPHASE(2)
    GPHASE(3)
    cur = nxt;
  }
#undef GPHASE

  // epilogue: ng = n0 + w*32 + j*16 + li; rows mgb = m0 + i*16 + lg*4 (+r)
  // Q scaled to exp2 domain; V stored transposed with short4 vector along t.
#pragma unroll
  for (int i = 0; i < 16; ++i) {
#pragma unroll
    for (int j = 0; j < 2; ++j) {
      const int ng = n0 + w * 32 + j * 16 + li;
      const float bs = bias[ng];
      const int mgb = m0 + i * 16 + lg * 4;
      const int bb = mgb >> 11, t = mgb & 2047;
      const int d = ng & 63;
      if (ng < 1024) {
        const int h = ng >> 6;
#pragma unroll
        for (int r = 0; r < 4; ++r)
          Qo[(((size_t)bb * 16 + h) * 2048 + t + r) * 64 + d] =
              __float2bfloat16((acc[i][j][r] + bs) * LOG2E_O8);
      } else if (ng < 2048) {
        const int h = (ng - 1024) >> 6;
#pragma unroll
        for (int r = 0; r < 4; ++r)
          Ko[(((size_t)bb * 16 + h) * 2048 + t + r) * 64 + d] =
              __float2bfloat16(acc[i][j][r] + bs);
      } else {
        const int h = (ng - 2048) >> 6;
        short4v vv;
#pragma unroll
        for (int r = 0; r < 4; ++r) vv[r] = (short)f2b(acc[i][j][r] + bs);
        *(short4v*)&Vo[(((size_t)bb * 16 + h) * 64 + d) * 2048 + t] = vv;
      }
    }
  }
}

// ---------------- GEMM v2 (GEMM2 only): 128x128, BK=32, counted vmcnt dbuf ----------------
__global__ __launch_bounds__(256) void k_gemm(
    const bf16* __restrict__ A, const bf16* __restrict__ Bt,
    const float* __restrict__ bias, float* __restrict__ Fo, int N, int Kd) {
  __shared__ bf16 sA[2][128 * 32];
  __shared__ bf16 sB[2][128 * 32];
  const int tid = threadIdx.x;
  const int w = tid >> 6, l = tid & 63;
  const int lg = l >> 4, li = l & 15;
  const int wr = w >> 1, wc = w & 1;
  const int ii = blockIdx.x >> 3, xcd = blockIdx.x & 7;
  const int bx = ii >> 3, by = xcd * 8 + (ii & 7);
  const int m0 = by * 128, n0 = bx * 128;

  const int r0 = tid >> 2, ko0 = (tid & 3) * 8;
  const bf16* pa0 = A + (size_t)(m0 + r0) * Kd + ko0;
  const bf16* pa1 = A + (size_t)(m0 + 64 + r0) * Kd + ko0;
  const bf16* pb0 = Bt + (size_t)(n0 + r0) * Kd + ko0;
  const bf16* pb1 = Bt + (size_t)(n0 + 64 + r0) * Kd + ko0;

  floatx4 acc[4][4];
#pragma unroll
  for (int i = 0; i < 4; ++i)
#pragma unroll
    for (int j = 0; j < 4; ++j) acc[i][j] = fzero4();

  auto STAGE = [&](int buf, int k0) {
    gload16(pa0 + k0, &sA[buf][w * 512]);
    gload16(pa1 + k0, &sA[buf][2048 + w * 512]);
    gload16(pb0 + k0, &sB[buf][w * 512]);
    gload16(pb1 + k0, &sB[buf][2048 + w * 512]);
  };

  STAGE(0, 0);
  int cur = 0;
  for (int k0 = 0; k0 < Kd; k0 += 32) {
    if (k0 + 32 < Kd) {
      STAGE(cur ^ 1, k0 + 32);
      asm volatile("s_waitcnt vmcnt(4)" ::: "memory");
    } else {
      asm volatile("s_waitcnt vmcnt(0)" ::: "memory");
    }
    __builtin_amdgcn_s_barrier();
    short8 af[4], bfr[4];
#pragma unroll
    for (int i = 0; i < 4; ++i)
      af[i] = *(const short8*)&sA[cur][(wr * 64 + i * 16 + li) * 32 + lg * 8];
#pragma unroll
    for (int j = 0; j < 4; ++j)
      bfr[j] = *(const short8*)&sB[cur][(wc * 64 + j * 16 + li) * 32 + lg * 8];
#pragma unroll
    for (int i = 0; i < 4; ++i)
#pragma unroll
      for (int j = 0; j < 4; ++j)
        acc[i][j] = __builtin_amdgcn_mfma_f32_16x16x32_bf16(af[i], bfr[j], acc[i][j], 0, 0, 0);
    __builtin_amdgcn_s_barrier();
    cur ^= 1;
  }

#pragma unroll
  for (int i = 0; i < 4; ++i) {
#pragma unroll
    for (int j = 0; j < 4; ++j) {
      const int ng = n0 + wc * 64 + j * 16 + li;
      const float bs = bias[ng];
      const int mgb = m0 + wr * 64 + i * 16 + lg * 4;
#pragma unroll
      for (int r = 0; r < 4; ++r)
        Fo[(size_t)(mgb + r) * N + ng] = acc[i][j][r] + bs;
    }
  }
}

// ---------------- flash attention v7 (unchanged) ----------------
#define T_SEQ 2048

__global__ __launch_bounds__(256) void k_attn(
    const bf16* __restrict__ Q, const bf16* __restrict__ K,
    const bf16* __restrict__ Vt, bf16* __restrict__ Y) {
  __shared__ bf16 sK[2][64 * 64];
  __shared__ bf16 sV[2][64 * 64];

  const int tid = threadIdx.x;
  const int w = tid >> 6, l = tid & 63;
  const int lg = l >> 4, li = l & 15;
  const int bid = blockIdx.x;
  const int sq = bid >> 3;
  const int bh = (bid & 7) * 8 + (sq & 7);
  const int g = sq >> 3;
  const int qd = g >> 2, rr = g & 3;
  const int tb = (qd == 0) ? 15 - rr : (qd == 1) ? 8 + rr : (qd == 2) ? 7 - rr : rr;
  const int b = bh >> 4, h = bh & 15;

  const bf16* Qp = Q + (size_t)bh * (T_SEQ * 64);
  const bf16* Kp = K + (size_t)bh * (T_SEQ * 64);
  const bf16* Vp = Vt + (size_t)bh * (64 * T_SEQ);

  const int q0 = tb * 128;
  const int wq0 = q0 + w * 32;
  const int nst = (q0 + 128) >> 6;

  short8 aq[2][2];
#pragma unroll
  for (int rg = 0; rg < 2; ++rg)
#pragma unroll
    for (int dc = 0; dc < 2; ++dc)
      aq[rg][dc] = *(const short8*)(Qp + (size_t)(wq0 + rg * 16 + li) * 64 + dc * 32 + lg * 8);

  floatx4 o[2][4];
#pragma unroll
  for (int rg = 0; rg < 2; ++rg)
#pragma unroll
    for (int f = 0; f < 4; ++f) o[rg][f] = fzero4();
  float m[2] = {-INFINITY, -INFINITY};
  float lsum[2] = {0.f, 0.f};

  auto STAGE = [&](int buf, int k0) {
#pragma unroll
    for (int half = 0; half < 2; ++half) {
      const int c = half * 256 + tid;
      const int row = c >> 3, cs = c & 7;
      const int sc = cs ^ (row & 7);
      bf16* kb = &sK[buf][(half * 256 + w * 64) * 8];
      bf16* vb = &sV[buf][(half * 256 + w * 64) * 8];
      gload16(Kp + (size_t)(k0 + row) * 64 + sc * 8, kb);
      gload16(Vp + (size_t)row * T_SEQ + k0 + sc * 8, vb);
    }
  };

  int cur = 0;
  STAGE(0, 0);
  for (int t = 0; t < nst; ++t) {
    const int k0 = t << 6;
    if (t + 1 < nst) {
      STAGE(cur ^ 1, k0 + 64);
      asm volatile("s_waitcnt vmcnt(4)" ::: "memory");
    } else {
      asm volatile("s_waitcnt vmcnt(0)" ::: "memory");
    }
    __builtin_amdgcn_s_barrier();
    if (k0 <= wq0 + 31) {
      floatx4 s[2][4];
      __builtin_amdgcn_s_setprio(1);
#pragma unroll
      for (int kt = 0; kt < 4; ++kt) {
        const int rowk = kt * 16 + li;
        const short8 kb0 = *(const short8*)&sK[cur][rowk * 64 + ((lg ^ (rowk & 7)) * 8)];
        const short8 kb1 = *(const short8*)&sK[cur][rowk * 64 + (((4 + lg) ^ (rowk & 7)) * 8)];
#pragma unroll
        for (int rg = 0; rg < 2; ++rg) {
          floatx4 acc = __builtin_amdgcn_mfma_f32_16x16x32_bf16(kb0, aq[rg][0], fzero4(), 0, 0, 0);
          s[rg][kt] = __builtin_amdgcn_mfma_f32_16x16x32_bf16(kb1, aq[rg][1], acc, 0, 0, 0);
        }
      }
      __builtin_amdgcn_s_setprio(0);
      if (k0 + 63 > wq0) {
#pragma unroll
        for (int rg = 0; rg < 2; ++rg) {
          const int qg = wq0 + rg * 16 + li;
#pragma unroll
          for (int kt = 0; kt < 4; ++kt) {
            const int kgb = k0 + kt * 16 + lg * 4;
#pragma unroll
            for (int r = 0; r < 4; ++r)
              if (kgb + r > qg) s[rg][kt][r] = -1e30f;
          }
        }
      }
      float pm[2];
#pragma unroll
      for (int rg = 0; rg < 2; ++rg) {
        float t0 = max3f(s[rg][0][0], s[rg][0][1], s[rg][0][2]);
        float t1 = max3f(s[rg][0][3], s[rg][1][0], s[rg][1][1]);
        float t2 = max3f(s[rg][1][2], s[rg][1][3], s[rg][2][0]);
        float t3 = max3f(s[rg][2][1], s[rg][2][2], s[rg][2][3]);
        float t4 = max3f(s[rg][3][0], s[rg][3][1], s[rg][3][2]);
        float p = fmaxf(max3f(t0, t1, t2), max3f(t3, t4, s[rg][3][3]));
        p = fmaxf(p, __shfl_xor(p, 16));
        p = fmaxf(p, __shfl_xor(p, 32));
        pm[rg] = p;
      }
      const float need = fmaxf(pm[0] - m[0], pm[1] - m[1]);
      if (!__all(need <= 8.0f)) {
#pragma unroll
        for (int rg = 0; rg < 2; ++rg) {
          const float mn = fmaxf(m[rg], pm[rg]);
          const float a = ex2(m[rg] - mn);
          m[rg] = mn;
          lsum[rg] *= a;
          float ar[4];
#pragma unroll
          for (int r = 0; r < 4; ++r) ar[r] = __shfl(a, lg * 4 + r);
#pragma unroll
          for (int f = 0; f < 4; ++f) {
            o[rg][f][0] *= ar[0]; o[rg][f][1] *= ar[1];
            o[rg][f][2] *= ar[2]; o[rg][f][3] *= ar[3];
          }
        }
      }
      short4v pa4[2][4];
#pragma unroll
      for (int rg = 0; rg < 2; ++rg) {
#pragma unroll
        for (int kt = 0; kt < 4; ++kt) {
          const float e0 = ex2(s[rg][kt][0] - m[rg]);
          const float e1 = ex2(s[rg][kt][1] - m[rg]);
          const float e2 = ex2(s[rg][kt][2] - m[rg]);
          const float e3 = ex2(s[rg][kt][3] - m[rg]);
          lsum[rg] += (e0 + e1) + (e2 + e3);
          short4v pv;
          pv[0] = (short)f2b(e0); pv[1] = (short)f2b(e1);
          pv[2] = (short)f2b(e2); pv[3] = (short)f2b(e3);
          pa4[rg][kt] = pv;
        }
      }
      __builtin_amdgcn_s_setprio(1);
#pragma unroll
      for (int f = 0; f < 4; ++f) {
        const int rowv = f * 16 + li;
        const int rx = rowv & 7;
#pragma unroll
        for (int kt = 0; kt < 4; ++kt) {
          const int cc = 2 * kt + (lg >> 1);
          const short4v vb4 = *(const short4v*)&sV[cur][rowv * 64 + (((cc ^ rx) << 3) | ((lg & 1) << 2))];
          o[0][f] = mfma16(pa4[0][kt], vb4, o[0][f]);
          o[1][f] = mfma16(pa4[1][kt], vb4, o[1][f]);
        }
      }
      __builtin_amdgcn_s_setprio(0);
    }
    __builtin_amdgcn_s_barrier();
    cur ^= 1;
  }
#pragma unroll
  for (int rg = 0; rg < 2; ++rg) {
    float Ls = lsum[rg];
    Ls += __shfl_xor(Ls, 16);
    Ls += __shfl_xor(Ls, 32);
#pragma unroll
    for (int r = 0; r < 4; ++r) {
      const float inv = 1.0f / __shfl(Ls, lg * 4 + r);
      const int qg = wq0 + rg * 16 + lg * 4 + r;
      const size_t base = ((size_t)b * T_SEQ + qg) * 1024 + h * 64;
#pragma unroll
      for (int f = 0; f < 4; ++f)
        Y[base + f * 16 + li] = __float2bfloat16(o[rg][f][r] * inv);
    }
  }
}

// ---------------- launch ----------------
extern "C" void kernel_launch(void* const* d_in, const int* in_sizes, int n_in,
                              void* d_out, int out_size, void* d_ws, size_t ws_size,
                              hipStream_t stream) {
  const float* x      = (const float*)d_in[0];
  const float* W_attn = (const float*)d_in[1];
  const float* b_attn = (const float*)d_in[2];
  const float* W_proj = (const float*)d_in[3];
  const float* b_proj = (const float*)d_in[4];
  float* out = (float*)d_out;

  char* ws = (char*)d_ws;
  bf16* Wt_a = (bf16*)(ws);
  bf16* Wt_p = (bf16*)(ws + 6291456);
  bf16* Qb   = (bf16*)(ws + 8388608);
  bf16* Kb   = (bf16*)(ws + 25165824);
  bf16* Vtb  = (bf16*)(ws + 41943040);
  bf16* x_bf = (bf16*)(ws + 58720256);
  bf16* Yb   = x_bf;  // alias: x_bf dead after GEMM1

  k_cast<<<4096, 256, 0, stream>>>(x, x_bf, 8388608);
  k_transpose<<<dim3(96, 32), dim3(32, 8), 0, stream>>>(W_attn, Wt_a, 1024, 3072);
  k_transpose<<<dim3(32, 32), dim3(32, 8), 0, stream>>>(W_proj, Wt_p, 1024, 1024);
  // GEMM1: 8-phase 256^2, grid 12x32 = 384 blocks of 512 threads
  k_gemm8<<<384, 512, 0, stream>>>(x_bf, Wt_a, b_attn, Qb, Kb, Vtb);
  k_attn<<<1024, 256, 0, stream>>>(Qb, Kb, Vtb, Yb);
  // GEMM2: v2 128^2, 8x64 = 512 blocks
  k_gemm<<<512, 256, 0, stream>>>(Yb, Wt_p, b_proj, out, 1024, 1024);
}

// Round 19
// 189.593 us; speedup vs baseline: 1.1997x; 1.0782x over previous
//
#include <hip/hip_runtime.h>
#include <hip/hip_bf16.h>
#include <math.h>

typedef __attribute__((ext_vector_type(8))) short short8;
typedef __attribute__((ext_vector_type(4))) short short4v;
typedef __attribute__((ext_vector_type(4))) float floatx4;
using bf16 = __hip_bfloat16;

#define DEVI __device__ __forceinline__

DEVI floatx4 fzero4() { floatx4 z; z[0]=0.f; z[1]=0.f; z[2]=0.f; z[3]=0.f; return z; }

// hardware exp2: v_exp_f32 computes 2^x (ISA §3).
DEVI float ex2(float x) {
  float r;
  asm("v_exp_f32 %0, %1" : "=v"(r) : "v"(x));
  return r;
}

// 3-input max, single VOP3 inst (T17).
DEVI float max3f(float a, float b, float c) {
  float d;
  asm("v_max3_f32 %0, %1, %2, %3" : "=v"(d) : "v"(a), "v"(b), "v"(c));
  return d;
}

DEVI unsigned short f2b(float x) {
  union { bf16 h; unsigned short u; } c;
  c.h = __float2bfloat16(x);
  return c.u;
}

// K=16 bf16 MFMA: A-frag = 4 bf16 at k=lg*4+j -- matches QK C/D output layout,
// so P feeds PV directly from registers (no LDS round-trip).
DEVI floatx4 mfma16(short4v a, short4v b, floatx4 c) {
#if __has_builtin(__builtin_amdgcn_mfma_f32_16x16x16bf16_1k)
  return __builtin_amdgcn_mfma_f32_16x16x16bf16_1k(a, b, c, 0, 0, 0);
#else
  floatx4 d;
  asm("v_mfma_f32_16x16x16_bf16 %0, %1, %2, %3" : "=v"(d) : "v"(a), "v"(b), "v"(c));
  return d;
#endif
}

// async global->LDS, 16B per lane; lds dest must be wave-uniform base (+lane*16 implicit)
DEVI void gload16(const bf16* g, bf16* l) {
  typedef __attribute__((address_space(1))) const void gv_t;
  typedef __attribute__((address_space(3))) void lv_t;
  __builtin_amdgcn_global_load_lds((gv_t*)g, (lv_t*)l, 16, 0, 0);
}

// ---------------- transpose + cast: out[c][r] = in[r][c] ----------------
__global__ __launch_bounds__(256) void k_transpose(const float* __restrict__ in,
                                                   bf16* __restrict__ out,
                                                   int R, int C) {
  __shared__ float tile[32][33];
  int x = blockIdx.x * 32 + threadIdx.x;
  for (int i = threadIdx.y; i < 32; i += 8) {
    int y = blockIdx.y * 32 + i;
    tile[i][threadIdx.x] = (y < R && x < C) ? in[(size_t)y * C + x] : 0.f;
  }
  __syncthreads();
  int ox = blockIdx.y * 32 + threadIdx.x;
  for (int i = threadIdx.y; i < 32; i += 8) {
    int oy = blockIdx.x * 32 + i;
    if (oy < C && ox < R) out[(size_t)oy * R + ox] = __float2bfloat16(tile[threadIdx.x][i]);
  }
}

// ---------------- GEMM1 (fused cast): C = f32 A[M,K] @ bf16 Bt[N,K]^T + bias ----------------
// 128x128 tile, BK=32, 4 waves.  B staged via gload16 dbuf (v2 pattern, vmcnt(6)
// counted: B(T) retires at top of T with a full iteration of slack).  A loaded
// f32->regs at iteration top (4x dwordx4, compiler-tracked), converted to bf16 and
// ds_write'd into buf nxt AFTER the MFMA section (T14 issue-early/write-late);
// lgkmcnt(0) publishes the writes before barrier#2.  Epilogue scatters Q/K/Vt.
#define LOG2E_O8 0.18033688011112042f

__global__ __launch_bounds__(256) void k_gemmA(
    const float* __restrict__ Ax, const bf16* __restrict__ Bt,
    const float* __restrict__ bias,
    bf16* __restrict__ Qo, bf16* __restrict__ Ko, bf16* __restrict__ Vo) {
  __shared__ bf16 sA[2][128 * 32];
  __shared__ bf16 sB[2][128 * 32];
  const int Kd = 1024;
  const int tid = threadIdx.x;
  const int w = tid >> 6, l = tid & 63;
  const int lg = l >> 4, li = l & 15;
  const int wr = w >> 1, wc = w & 1;
  const int ii = blockIdx.x >> 3, xcd = blockIdx.x & 7;
  const int bx = ii >> 3, by = xcd * 8 + (ii & 7);
  const int m0 = by * 128, n0 = bx * 128;

  const int r0 = tid >> 2, ko0 = (tid & 3) * 8;
  const float* pax0 = Ax + (size_t)(m0 + r0) * Kd + ko0;
  const float* pax1 = Ax + (size_t)(m0 + 64 + r0) * Kd + ko0;
  const bf16* pb0 = Bt + (size_t)(n0 + r0) * Kd + ko0;
  const bf16* pb1 = Bt + (size_t)(n0 + 64 + r0) * Kd + ko0;

  floatx4 acc[4][4];
#pragma unroll
  for (int i = 0; i < 4; ++i)
#pragma unroll
    for (int j = 0; j < 4; ++j) acc[i][j] = fzero4();

  float4 va0, va1, va2, va3;   // A f32 staging regs (tile T+1)

  auto ISSUE_A = [&](int k0) {
    va0 = *(const float4*)(pax0 + k0);
    va1 = *(const float4*)(pax0 + k0 + 4);
    va2 = *(const float4*)(pax1 + k0);
    va3 = *(const float4*)(pax1 + k0 + 4);
  };
  auto WRITE_A = [&](int buf) {   // compiler inserts vmcnt wait before va uses
    short8 s0, s1;
    s0[0] = (short)f2b(va0.x); s0[1] = (short)f2b(va0.y);
    s0[2] = (short)f2b(va0.z); s0[3] = (short)f2b(va0.w);
    s0[4] = (short)f2b(va1.x); s0[5] = (short)f2b(va1.y);
    s0[6] = (short)f2b(va1.z); s0[7] = (short)f2b(va1.w);
    s1[0] = (short)f2b(va2.x); s1[1] = (short)f2b(va2.y);
    s1[2] = (short)f2b(va2.z); s1[3] = (short)f2b(va2.w);
    s1[4] = (short)f2b(va3.x); s1[5] = (short)f2b(va3.y);
    s1[6] = (short)f2b(va3.z); s1[7] = (short)f2b(va3.w);
    *(short8*)&sA[buf][r0 * 32 + ko0] = s0;
    *(short8*)&sA[buf][(64 + r0) * 32 + ko0] = s1;
  };
  auto STAGE_B = [&](int buf, int k0) {
    gload16(pb0 + k0, &sB[buf][w * 512]);
    gload16(pb1 + k0, &sB[buf][2048 + w * 512]);
  };

  // prologue: tile 0 -> buf 0
  ISSUE_A(0);
  STAGE_B(0, 0);
  WRITE_A(0);
  asm volatile("s_waitcnt lgkmcnt(0)" ::: "memory");
  // outstanding: B(0) x2

  int cur = 0;
  for (int k0 = 0; k0 < Kd; k0 += 32) {
    const int nxt = cur ^ 1;
    const bool pf = (k0 + 32 < Kd);
    if (pf) {
      ISSUE_A(k0 + 32);                                  // +4 (regs)
      STAGE_B(nxt, k0 + 32);                             // +2
      asm volatile("s_waitcnt vmcnt(6)" ::: "memory");   // retire B(cur)
    } else {
      asm volatile("s_waitcnt vmcnt(0)" ::: "memory");   // last tile: drain B
    }
    __builtin_amdgcn_s_barrier();                        // buf cur published
    short8 af[4], bfr[4];
#pragma unroll
    for (int i = 0; i < 4; ++i)
      af[i] = *(const short8*)&sA[cur][(wr * 64 + i * 16 + li) * 32 + lg * 8];
#pragma unroll
    for (int j = 0; j < 4; ++j)
      bfr[j] = *(const short8*)&sB[cur][(wc * 64 + j * 16 + li) * 32 + lg * 8];
#pragma unroll
    for (int i = 0; i < 4; ++i)
#pragma unroll
      for (int j = 0; j < 4; ++j)
        acc[i][j] = __builtin_amdgcn_mfma_f32_16x16x32_bf16(af[i], bfr[j], acc[i][j], 0, 0, 0);
    if (pf) {
      WRITE_A(nxt);                                      // cvt + ds_write A(T+1)
      asm volatile("s_waitcnt lgkmcnt(0)" ::: "memory"); // publish ds_writes
    }
    __builtin_amdgcn_s_barrier();                        // all waves done with cur
    cur = nxt;
  }

  // epilogue: D frag mapping col = li, row = lg*4 + r  [m89/m91 verified]
  // Q pre-scaled by log2(e)/8 (exp2-domain attention); V stored transposed
  // with short4 vector along t.
#pragma unroll
  for (int i = 0; i < 4; ++i) {
#pragma unroll
    for (int j = 0; j < 4; ++j) {
      const int ng = n0 + wc * 64 + j * 16 + li;
      const float bs = bias[ng];
      const int mgb = m0 + wr * 64 + i * 16 + lg * 4;
      const int bb = mgb >> 11, t = mgb & 2047;
      const int d = ng & 63;
      if (ng < 1024) {
        const int h = ng >> 6;
#pragma unroll
        for (int r = 0; r < 4; ++r)
          Qo[(((size_t)bb * 16 + h) * 2048 + t + r) * 64 + d] =
              __float2bfloat16((acc[i][j][r] + bs) * LOG2E_O8);
      } else if (ng < 2048) {
        const int h = (ng - 1024) >> 6;
#pragma unroll
        for (int r = 0; r < 4; ++r)
          Ko[(((size_t)bb * 16 + h) * 2048 + t + r) * 64 + d] =
              __float2bfloat16(acc[i][j][r] + bs);
      } else {
        const int h = (ng - 2048) >> 6;
        short4v vv;
#pragma unroll
        for (int r = 0; r < 4; ++r) vv[r] = (short)f2b(acc[i][j][r] + bs);
        *(short4v*)&Vo[(((size_t)bb * 16 + h) * 64 + d) * 2048 + t] = vv;
      }
    }
  }
}

// ---------------- GEMM v2 (GEMM2): 128x128, BK=32, counted vmcnt dbuf ----------------
__global__ __launch_bounds__(256) void k_gemm(
    const bf16* __restrict__ A, const bf16* __restrict__ Bt,
    const float* __restrict__ bias, float* __restrict__ Fo, int N, int Kd) {
  __shared__ bf16 sA[2][128 * 32];
  __shared__ bf16 sB[2][128 * 32];
  const int tid = threadIdx.x;
  const int w = tid >> 6, l = tid & 63;
  const int lg = l >> 4, li = l & 15;
  const int wr = w >> 1, wc = w & 1;
  const int ii = blockIdx.x >> 3, xcd = blockIdx.x & 7;
  const int bx = ii >> 3, by = xcd * 8 + (ii & 7);
  const int m0 = by * 128, n0 = bx * 128;

  const int r0 = tid >> 2, ko0 = (tid & 3) * 8;
  const bf16* pa0 = A + (size_t)(m0 + r0) * Kd + ko0;
  const bf16* pa1 = A + (size_t)(m0 + 64 + r0) * Kd + ko0;
  const bf16* pb0 = Bt + (size_t)(n0 + r0) * Kd + ko0;
  const bf16* pb1 = Bt + (size_t)(n0 + 64 + r0) * Kd + ko0;

  floatx4 acc[4][4];
#pragma unroll
  for (int i = 0; i < 4; ++i)
#pragma unroll
    for (int j = 0; j < 4; ++j) acc[i][j] = fzero4();

  auto STAGE = [&](int buf, int k0) {
    gload16(pa0 + k0, &sA[buf][w * 512]);
    gload16(pa1 + k0, &sA[buf][2048 + w * 512]);
    gload16(pb0 + k0, &sB[buf][w * 512]);
    gload16(pb1 + k0, &sB[buf][2048 + w * 512]);
  };

  STAGE(0, 0);
  int cur = 0;
  for (int k0 = 0; k0 < Kd; k0 += 32) {
    if (k0 + 32 < Kd) {
      STAGE(cur ^ 1, k0 + 32);
      asm volatile("s_waitcnt vmcnt(4)" ::: "memory");
    } else {
      asm volatile("s_waitcnt vmcnt(0)" ::: "memory");
    }
    __builtin_amdgcn_s_barrier();
    short8 af[4], bfr[4];
#pragma unroll
    for (int i = 0; i < 4; ++i)
      af[i] = *(const short8*)&sA[cur][(wr * 64 + i * 16 + li) * 32 + lg * 8];
#pragma unroll
    for (int j = 0; j < 4; ++j)
      bfr[j] = *(const short8*)&sB[cur][(wc * 64 + j * 16 + li) * 32 + lg * 8];
#pragma unroll
    for (int i = 0; i < 4; ++i)
#pragma unroll
      for (int j = 0; j < 4; ++j)
        acc[i][j] = __builtin_amdgcn_mfma_f32_16x16x32_bf16(af[i], bfr[j], acc[i][j], 0, 0, 0);
    __builtin_amdgcn_s_barrier();
    cur ^= 1;
  }

#pragma unroll
  for (int i = 0; i < 4; ++i) {
#pragma unroll
    for (int j = 0; j < 4; ++j) {
      const int ng = n0 + wc * 64 + j * 16 + li;
      const float bs = bias[ng];
      const int mgb = m0 + wr * 64 + i * 16 + lg * 4;
#pragma unroll
      for (int r = 0; r < 4; ++r)
        Fo[(size_t)(mgb + r) * N + ng] = acc[i][j][r] + bs;
    }
  }
}

// ---------------- flash attention v7: balanced dispatch + setprio + max3 ----------------
#define T_SEQ 2048

__global__ __launch_bounds__(256) void k_attn(
    const bf16* __restrict__ Q, const bf16* __restrict__ K,
    const bf16* __restrict__ Vt, bf16* __restrict__ Y) {
  __shared__ bf16 sK[2][64 * 64];
  __shared__ bf16 sV[2][64 * 64];

  const int tid = threadIdx.x;
  const int w = tid >> 6, l = tid & 63;
  const int lg = l >> 4, li = l & 15;
  const int bid = blockIdx.x;
  const int sq = bid >> 3;
  const int bh = (bid & 7) * 8 + (sq & 7);  // all 16 tiles of a head on one XCD
  const int g = sq >> 3;                    // 0..15, dispatch order
  const int qd = g >> 2, rr = g & 3;        // balanced map: {15,8,7,0} etc per CU
  const int tb = (qd == 0) ? 15 - rr : (qd == 1) ? 8 + rr : (qd == 2) ? 7 - rr : rr;
  const int b = bh >> 4, h = bh & 15;

  const bf16* Qp = Q + (size_t)bh * (T_SEQ * 64);
  const bf16* Kp = K + (size_t)bh * (T_SEQ * 64);
  const bf16* Vp = Vt + (size_t)bh * (64 * T_SEQ);

  const int q0 = tb * 128;
  const int wq0 = q0 + w * 32;
  const int nst = (q0 + 128) >> 6;

  // Q B-frags (swapped mfma): row q = wq0+rg*16+li, d-chunk dc*32+lg*8
  short8 aq[2][2];
#pragma unroll
  for (int rg = 0; rg < 2; ++rg)
#pragma unroll
    for (int dc = 0; dc < 2; ++dc)
      aq[rg][dc] = *(const short8*)(Qp + (size_t)(wq0 + rg * 16 + li) * 64 + dc * 32 + lg * 8);

  floatx4 o[2][4];
#pragma unroll
  for (int rg = 0; rg < 2; ++rg)
#pragma unroll
    for (int f = 0; f < 4; ++f) o[rg][f] = fzero4();
  float m[2] = {-INFINITY, -INFINITY};
  float lsum[2] = {0.f, 0.f};   // partial over this lane's 16-k groups

  auto STAGE = [&](int buf, int k0) {
#pragma unroll
    for (int half = 0; half < 2; ++half) {
      const int c = half * 256 + tid;
      const int row = c >> 3, cs = c & 7;
      const int sc = cs ^ (row & 7);
      bf16* kb = &sK[buf][(half * 256 + w * 64) * 8];
      bf16* vb = &sV[buf][(half * 256 + w * 64) * 8];
      gload16(Kp + (size_t)(k0 + row) * 64 + sc * 8, kb);
      gload16(Vp + (size_t)row * T_SEQ + k0 + sc * 8, vb);
    }
  };

  int cur = 0;
  STAGE(0, 0);
  for (int t = 0; t < nst; ++t) {
    const int k0 = t << 6;
    if (t + 1 < nst) {
      STAGE(cur ^ 1, k0 + 64);                          // prefetch stays in flight
      asm volatile("s_waitcnt vmcnt(4)" ::: "memory");  // tile-t loads landed
    } else {
      asm volatile("s_waitcnt vmcnt(0)" ::: "memory");  // last tile: drain
    }
    __builtin_amdgcn_s_barrier();                       // all waves' tile-t landed
    if (k0 <= wq0 + 31) {
      // ---- swapped QK^T: s[rg][kt]: lane holds q=li(+rg*16), k=kt*16+lg*4+r ----
      floatx4 s[2][4];
      __builtin_amdgcn_s_setprio(1);
#pragma unroll
      for (int kt = 0; kt < 4; ++kt) {
        const int rowk = kt * 16 + li;
        const short8 kb0 = *(const short8*)&sK[cur][rowk * 64 + ((lg ^ (rowk & 7)) * 8)];
        const short8 kb1 = *(const short8*)&sK[cur][rowk * 64 + (((4 + lg) ^ (rowk & 7)) * 8)];
#pragma unroll
        for (int rg = 0; rg < 2; ++rg) {
          floatx4 acc = __builtin_amdgcn_mfma_f32_16x16x32_bf16(kb0, aq[rg][0], fzero4(), 0, 0, 0);
          s[rg][kt] = __builtin_amdgcn_mfma_f32_16x16x32_bf16(kb1, aq[rg][1], acc, 0, 0, 0);
        }
      }
      __builtin_amdgcn_s_setprio(0);
      // ---- causal mask (diagonal steps only) ----
      if (k0 + 63 > wq0) {
#pragma unroll
        for (int rg = 0; rg < 2; ++rg) {
          const int qg = wq0 + rg * 16 + li;
#pragma unroll
          for (int kt = 0; kt < 4; ++kt) {
            const int kgb = k0 + kt * 16 + lg * 4;
#pragma unroll
            for (int r = 0; r < 4; ++r)
              if (kgb + r > qg) s[rg][kt][r] = -1e30f;
          }
        }
      }
      // ---- row max: v_max3 tree + 2-hop shfl reduce ----
      float pm[2];
#pragma unroll
      for (int rg = 0; rg < 2; ++rg) {
        float t0 = max3f(s[rg][0][0], s[rg][0][1], s[rg][0][2]);
        float t1 = max3f(s[rg][0][3], s[rg][1][0], s[rg][1][1]);
        float t2 = max3f(s[rg][1][2], s[rg][1][3], s[rg][2][0]);
        float t3 = max3f(s[rg][2][1], s[rg][2][2], s[rg][2][3]);
        float t4 = max3f(s[rg][3][0], s[rg][3][1], s[rg][3][2]);
        float p = fmaxf(max3f(t0, t1, t2), max3f(t3, t4, s[rg][3][3]));
        p = fmaxf(p, __shfl_xor(p, 16));
        p = fmaxf(p, __shfl_xor(p, 32));
        pm[rg] = p;
      }
      // ---- defer-max: rescale only when max grew by > 8 (log2 units) ----
      const float need = fmaxf(pm[0] - m[0], pm[1] - m[1]);
      if (!__all(need <= 8.0f)) {
#pragma unroll
        for (int rg = 0; rg < 2; ++rg) {
          const float mn = fmaxf(m[rg], pm[rg]);
          const float a = ex2(m[rg] - mn);
          m[rg] = mn;
          lsum[rg] *= a;
          float ar[4];
#pragma unroll
          for (int r = 0; r < 4; ++r) ar[r] = __shfl(a, lg * 4 + r);
#pragma unroll
          for (int f = 0; f < 4; ++f) {
            o[rg][f][0] *= ar[0]; o[rg][f][1] *= ar[1];
            o[rg][f][2] *= ar[2]; o[rg][f][3] *= ar[3];
          }
        }
      }
      // ---- exp2 -> P stays in registers as K=16 A-frags (k = kt*16+lg*4+r) ----
      short4v pa4[2][4];
#pragma unroll
      for (int rg = 0; rg < 2; ++rg) {
#pragma unroll
        for (int kt = 0; kt < 4; ++kt) {
          const float e0 = ex2(s[rg][kt][0] - m[rg]);
          const float e1 = ex2(s[rg][kt][1] - m[rg]);
          const float e2 = ex2(s[rg][kt][2] - m[rg]);
          const float e3 = ex2(s[rg][kt][3] - m[rg]);
          lsum[rg] += (e0 + e1) + (e2 + e3);
          short4v pv;
          pv[0] = (short)f2b(e0); pv[1] = (short)f2b(e1);
          pv[2] = (short)f2b(e2); pv[3] = (short)f2b(e3);
          pa4[rg][kt] = pv;
        }
      }
      // ---- PV: o[rg][f] += P @ V via 4x mfma16 per d-block (register A-frags) ----
      __builtin_amdgcn_s_setprio(1);
#pragma unroll
      for (int f = 0; f < 4; ++f) {
        const int rowv = f * 16 + li;
        const int rx = rowv & 7;
#pragma unroll
        for (int kt = 0; kt < 4; ++kt) {
          const int cc = 2 * kt + (lg >> 1);
          const short4v vb4 = *(const short4v*)&sV[cur][rowv * 64 + (((cc ^ rx) << 3) | ((lg & 1) << 2))];
          o[0][f] = mfma16(pa4[0][kt], vb4, o[0][f]);
          o[1][f] = mfma16(pa4[1][kt], vb4, o[1][f]);
        }
      }
      __builtin_amdgcn_s_setprio(0);
    }
    __builtin_amdgcn_s_barrier();                       // all waves done reading buf[cur]
    cur ^= 1;
  }
  // ---- epilogue: finish lsum reduce, broadcast inv to o rows, write Y ----
#pragma unroll
  for (int rg = 0; rg < 2; ++rg) {
    float Ls = lsum[rg];
    Ls += __shfl_xor(Ls, 16);
    Ls += __shfl_xor(Ls, 32);
#pragma unroll
    for (int r = 0; r < 4; ++r) {
      const float inv = 1.0f / __shfl(Ls, lg * 4 + r);
      const int qg = wq0 + rg * 16 + lg * 4 + r;
      const size_t base = ((size_t)b * T_SEQ + qg) * 1024 + h * 64;
#pragma unroll
      for (int f = 0; f < 4; ++f)
        Y[base + f * 16 + li] = __float2bfloat16(o[rg][f][r] * inv);
    }
  }
}

// ---------------- launch ----------------
extern "C" void kernel_launch(void* const* d_in, const int* in_sizes, int n_in,
                              void* d_out, int out_size, void* d_ws, size_t ws_size,
                              hipStream_t stream) {
  const float* x      = (const float*)d_in[0];
  const float* W_attn = (const float*)d_in[1];
  const float* b_attn = (const float*)d_in[2];
  const float* W_proj = (const float*)d_in[3];
  const float* b_proj = (const float*)d_in[4];
  float* out = (float*)d_out;

  char* ws = (char*)d_ws;
  bf16* Wt_a = (bf16*)(ws);
  bf16* Wt_p = (bf16*)(ws + 6291456);
  bf16* Qb   = (bf16*)(ws + 8388608);
  bf16* Kb   = (bf16*)(ws + 25165824);
  bf16* Vtb  = (bf16*)(ws + 41943040);
  bf16* Yb   = (bf16*)(ws + 58720256);   // attn output (x_bf eliminated)

  k_transpose<<<dim3(96, 32), dim3(32, 8), 0, stream>>>(W_attn, Wt_a, 1024, 3072);
  k_transpose<<<dim3(32, 32), dim3(32, 8), 0, stream>>>(W_proj, Wt_p, 1024, 1024);
  // GEMM1 with fused f32->bf16 A-cast: 24x64 = 1536 blocks, XCD-swizzled inside
  k_gemmA<<<1536, 256, 0, stream>>>(x, Wt_a, b_attn, Qb, Kb, Vtb);
  k_attn<<<1024, 256, 0, stream>>>(Qb, Kb, Vtb, Yb);
  // GEMM2: v2 128^2, 8x64 = 512 blocks
  k_gemm<<<512, 256, 0, stream>>>(Yb, Wt_p, b_proj, out, 1024, 1024);
}